// Round 4
// baseline (510.420 us; speedup 1.0000x reference)
//
#include <hip/hip_runtime.h>

// CausalSelfAttention: x[4,2048,1024] fp32 -> out fp32
// Pipeline (all bf16 MFMA, fp32 accum):
//  1) cvt x -> bf16            2) transpose+cvt W_attn & W_proj -> bf16 [N][K]
//  3) gemm_bt + bias -> Q (pre-scaled by 0.125*log2e) [b,h,s,d], K [b,h,s,d],
//     V TRANSPOSED [b,h,d,s]  (all bf16)
//  4) flash attention: fixed-max softmax (P = 2^s), K/Vt staged direct-to-LDS
//     via global_load_lds w/ XOR source swizzle; P roundtrip through LDS.
//  5) gemm_bt(Y, W_projT) + bias -> out fp32
// MFMA 16x16x32 bf16 layouts (HW-verified per guide):
//   A: a[j] = A[m=lane&15][k=quad*8+j]  (quad=lane>>4)
//   B: b[j] = B[k=quad*8+j][n=lane&15]
//   C/D: c[i] = D[row=quad*4+i][col=lane&15]

#define BATCH 4
#define SEQ   2048
#define EMB   1024
#define NH    16
#define HD    64

typedef __bf16 bf16;
typedef __bf16 bf16x8 __attribute__((ext_vector_type(8)));
typedef float  f32x4  __attribute__((ext_vector_type(4)));
typedef unsigned int u32x4 __attribute__((ext_vector_type(4)));

// direct global->LDS 16B copy: LDS dest is wave-uniform base + lane*16
__device__ __forceinline__ void ld_lds16(const void* g, void* l) {
  __builtin_amdgcn_global_load_lds(
      (const __attribute__((address_space(1))) void*)g,
      (__attribute__((address_space(3))) void*)l, 16, 0, 0);
}

// ---------------- convert fp32 -> bf16 ----------------
__global__ void cvt_f32_bf16(const float* __restrict__ in, bf16* __restrict__ out, int n) {
  int i = (blockIdx.x * blockDim.x + threadIdx.x) * 4;
  if (i + 3 < n) {
    float4 v = *(const float4*)(in + i);
    bf16 o0 = (bf16)v.x, o1 = (bf16)v.y, o2 = (bf16)v.z, o3 = (bf16)v.w;
    out[i] = o0; out[i+1] = o1; out[i+2] = o2; out[i+3] = o3;
  }
}

// ---------------- transpose + convert both weights (one launch) ----------------
// W[K=1024][N] fp32 -> WT[N][K] bf16.  blockIdx.x<96 -> W_attn(N=3072), else W_proj.
__global__ void transpose_cvt2(const float* __restrict__ Wa, const float* __restrict__ Wp,
                               bf16* __restrict__ WaT, bf16* __restrict__ WpT) {
  __shared__ float tile[32][33];
  int bx = blockIdx.x;
  const float* W; bf16* WT; int N;
  if (bx < 96) { W = Wa; WT = WaT; N = 3072; }
  else         { W = Wp; WT = WpT; N = 1024; bx -= 96; }
  int n0 = bx * 32, k0 = blockIdx.y * 32;
  int tx = threadIdx.x & 31, ty = threadIdx.x >> 5; // ty: 0..7
#pragma unroll
  for (int r = 0; r < 4; r++) {
    int k = k0 + ty + r * 8;
    tile[ty + r * 8][tx] = W[(long)k * N + n0 + tx];
  }
  __syncthreads();
#pragma unroll
  for (int r = 0; r < 4; r++) {
    int n = n0 + ty + r * 8;
    WT[(long)n * EMB + k0 + tx] = (bf16)tile[tx][ty + r * 8];
  }
}

// ---------------- GEMM: A[M][K] bf16 x Bt[N][K] bf16 + bias ----------------
// 128 x BNT tile, BK=32, direct-to-LDS staging (lane-linear) with XOR source
// swizzle: physical unit (row*4+u) holds logical chunk u^(row&3) -> fragment
// reads land 2-way-per-cycle on banks (free).  6 blocks/CU resident.
#define QSCALE 0.18033688f   // (1/8) * log2(e): folds attn scale + exp2 conversion

template <int BNT>
__global__ __launch_bounds__(256, 6) void gemm_bt(
    const bf16* __restrict__ A, const bf16* __restrict__ Bt,
    const float* __restrict__ bias, int Kdim, int Ncols, int mode,
    bf16* __restrict__ q, bf16* __restrict__ k, bf16* __restrict__ v,
    float* __restrict__ out)
{
  constexpr int NF = BNT / 32;               // n-fragments per wave
  __shared__ __align__(16) bf16 Al[128 * 32];
  __shared__ __align__(16) bf16 Bl[BNT * 32];
  int m0 = blockIdx.y * 128;
  int n0 = blockIdx.x * BNT;
  int t = threadIdx.x;
  int wave = t >> 6, lane = t & 63;
  int l15 = lane & 15, quad = lane >> 4;
  int wm = (wave & 1) * 64, wn = (wave >> 1) * (BNT / 2);

  f32x4 acc[4][NF] = {};

  for (int kt = 0; kt < Kdim; kt += 32) {
    __syncthreads();
#pragma unroll
    for (int it = 0; it < 2; ++it) {
      int c = it * 256 + t;
      int row = c >> 2, u = c & 3;
      ld_lds16(&A[(long)(m0 + row) * Kdim + kt + ((u ^ (row & 3)) * 8)],
               &Al[(it * 256 + wave * 64) * 8]);
    }
#pragma unroll
    for (int it = 0; it < BNT / 64; ++it) {
      int c = it * 256 + t;
      int row = c >> 2, u = c & 3;
      ld_lds16(&Bt[(long)(n0 + row) * Kdim + kt + ((u ^ (row & 3)) * 8)],
               &Bl[(it * 256 + wave * 64) * 8]);
    }
    __syncthreads();
    bf16x8 af[4], bfr[NF];
#pragma unroll
    for (int i = 0; i < 4; ++i) {
      int r = wm + i * 16 + l15;
      af[i] = *(const bf16x8*)(&Al[r * 32 + ((quad ^ (r & 3)) * 8)]);
    }
#pragma unroll
    for (int i = 0; i < NF; ++i) {
      int r = wn + i * 16 + l15;
      bfr[i] = *(const bf16x8*)(&Bl[r * 32 + ((quad ^ (r & 3)) * 8)]);
    }
#pragma unroll
    for (int mi = 0; mi < 4; ++mi)
#pragma unroll
      for (int ni = 0; ni < NF; ++ni)
        acc[mi][ni] = __builtin_amdgcn_mfma_f32_16x16x32_bf16(af[mi], bfr[ni], acc[mi][ni], 0, 0, 0);
  }

  // epilogue
#pragma unroll
  for (int mi = 0; mi < 4; ++mi) {
#pragma unroll
    for (int ni = 0; ni < NF; ++ni) {
      int gcol = n0 + wn + ni * 16 + l15;
      float bv = bias[gcol];
#pragma unroll
      for (int i = 0; i < 4; ++i) {
        int grow = m0 + wm + mi * 16 + quad * 4 + i;
        float val = acc[mi][ni][i] + bv;
        if (mode == 0) {
          int which = gcol >> 10, e = gcol & 1023;
          int h = e >> 6, d = e & 63;
          int b = grow >> 11, s = grow & 2047;
          if (which == 0) {
            q[(((long)b * NH + h) * SEQ + s) * HD + d] = (bf16)(val * QSCALE);
          } else if (which == 1) {
            k[(((long)b * NH + h) * SEQ + s) * HD + d] = (bf16)val;
          } else {
            v[(((long)b * NH + h) * HD + d) * SEQ + s] = (bf16)val;  // V^T
          }
        } else {
          out[(long)grow * Ncols + gcol] = val;
        }
      }
    }
  }
}

// ---------------- flash attention ----------------
// grid (16, B*NH); block 256 = 4 waves; block runs strips i and 31-i (balanced).
// 64-key tiles; K and V^T staged direct-to-LDS with XOR source swizzle so the
// lane-linear layout reads conflict-free. Fixed-max softmax: P = 2^s
// (Q pre-scaled by 0.125*log2e), l deferred to epilogue.
__global__ __launch_bounds__(256, 4) void attn(
    const bf16* __restrict__ Q, const bf16* __restrict__ K,
    const bf16* __restrict__ Vt, bf16* __restrict__ Y)
{
  __shared__ __align__(16) bf16 Kl[64 * 64];       // [key][d], units swizzled by key&7
  __shared__ __align__(16) bf16 Vl[64 * 64];       // [d][key], units swizzled by d&7
  __shared__ __align__(16) bf16 Pl[4][16 * 64];    // per-wave [q][col^swz]
  int b = blockIdx.y >> 4, h = blockIdx.y & 15;
  const bf16* Qp  = Q  + (((long)b * NH + h) * SEQ) * HD;
  const bf16* Kp  = K  + (((long)b * NH + h) * SEQ) * HD;
  const bf16* Vtp = Vt + (((long)b * NH + h) * HD) * SEQ;
  int t = threadIdx.x, wave = t >> 6, lane = t & 63;
  int l15 = lane & 15, quad = lane >> 4;

#pragma unroll 1
  for (int pass = 0; pass < 2; ++pass) {
    int q0 = (pass == 0) ? blockIdx.x * 64 : (SEQ - 64) - blockIdx.x * 64;
    int wq0 = q0 + wave * 16;

    // Q fragments: A[m=l15][k=quad*8+j], k split 0/32 (Q pre-scaled)
    bf16x8 qf0, qf1;
    {
      const bf16* qrow = Qp + (long)(wq0 + l15) * HD + quad * 8;
      qf0 = *(const bf16x8*)(qrow);
      qf1 = *(const bf16x8*)(qrow + 32);
    }
    float lrow[4] = {0.f, 0.f, 0.f, 0.f};
    f32x4 oacc[4] = {};

    int ntiles = q0 / 64 + 1;
#pragma unroll 1
    for (int kt = 0; kt < ntiles; ++kt) {
      int k0 = kt * 64;
      __syncthreads();
      // stage K [key][d] and V^T [d][key]; source-swizzled: LDS unit
      // (row*8 + u) holds global chunk (u ^ (row&7)) of that row.
#pragma unroll
      for (int it = 0; it < 2; ++it) {
        int cu = it * 256 + t;
        int row = cu >> 3, u = cu & 7;
        ld_lds16(&Kp[(long)(k0 + row) * HD + ((u ^ (row & 7)) * 8)],
                 &Kl[(it * 256 + wave * 64) * 8]);
        ld_lds16(&Vtp[(long)row * SEQ + k0 + ((u ^ (row & 7)) * 8)],
                 &Vl[(it * 256 + wave * 64) * 8]);
      }
      __syncthreads();

      // scores: S[16q x 64k] = Q @ K^T  (4 n-frags x 2 k-steps)
      f32x4 s[4] = {};
#pragma unroll
      for (int kk = 0; kk < 2; ++kk) {
        bf16x8 qf = kk ? qf1 : qf0;
#pragma unroll
        for (int ni = 0; ni < 4; ++ni) {
          int r = ni * 16 + l15, u = kk * 4 + quad;
          bf16x8 kfr = *(const bf16x8*)(&Kl[r * 64 + ((u ^ (r & 7)) * 8)]);
          s[ni] = __builtin_amdgcn_mfma_f32_16x16x32_bf16(qf, kfr, s[ni], 0, 0, 0);
        }
      }

      bool full = (k0 + 63 <= wq0);   // wave-uniform
#pragma unroll
      for (int i = 0; i < 4; ++i) {
        int qr = wq0 + quad * 4 + i;
        float e[4];
#pragma unroll
        for (int ni = 0; ni < 4; ++ni) {
          float x = s[ni][i];
          if (!full) x = (k0 + ni * 16 + l15 <= qr) ? x : -1e30f;
          e[ni] = __builtin_amdgcn_exp2f(x);   // P = 2^(score*log2e/8)
        }
        lrow[i] += (e[0] + e[1]) + (e[2] + e[3]);
        int prow = (quad * 4 + i) * 64;   // store col' = col ^ (quad*16)
        Pl[wave][prow + ((0 ^ quad) * 16 + l15)] = (bf16)e[0];
        Pl[wave][prow + ((1 ^ quad) * 16 + l15)] = (bf16)e[1];
        Pl[wave][prow + ((2 ^ quad) * 16 + l15)] = (bf16)e[2];
        Pl[wave][prow + ((3 ^ quad) * 16 + l15)] = (bf16)e[3];
      }
      asm volatile("s_waitcnt lgkmcnt(0)" ::: "memory");
      // PV: P[16x64] @ V[64x64]
#pragma unroll
      for (int kk = 0; kk < 2; ++kk) {
        int kbase = kk * 32 + quad * 8;
        bf16x8 pf = *(const bf16x8*)(&Pl[wave][l15 * 64 + (kbase ^ ((l15 >> 2) * 16))]);
#pragma unroll
        for (int ni = 0; ni < 4; ++ni) {
          int dd = ni * 16 + l15, u = kk * 4 + quad;
          bf16x8 vf = *(const bf16x8*)(&Vl[dd * 64 + ((u ^ (dd & 7)) * 8)]);
          oacc[ni] = __builtin_amdgcn_mfma_f32_16x16x32_bf16(pf, vf, oacc[ni], 0, 0, 0);
        }
      }
    }
    // epilogue: reduce l across the 16 q-columns group, write Y bf16
#pragma unroll
    for (int i = 0; i < 4; ++i) {
      float rs = lrow[i];
#pragma unroll
      for (int off = 8; off; off >>= 1) rs += __shfl_xor(rs, off, 16);
      float inv = 1.0f / rs;
      int qr = wq0 + quad * 4 + i;
      bf16* dst = Y + ((long)(b * SEQ + qr)) * EMB + h * HD;
#pragma unroll
      for (int ni = 0; ni < 4; ++ni)
        dst[ni * 16 + l15] = (bf16)(oacc[ni][i] * inv);
    }
  }
}

extern "C" void kernel_launch(void* const* d_in, const int* in_sizes, int n_in,
                              void* d_out, int out_size, void* d_ws, size_t ws_size,
                              hipStream_t stream) {
  const float* x      = (const float*)d_in[0];
  const float* W_attn = (const float*)d_in[1];
  const float* b_attn = (const float*)d_in[2];
  const float* W_proj = (const float*)d_in[3];
  const float* b_proj = (const float*)d_in[4];
  float* out = (float*)d_out;
  char* ws = (char*)d_ws;
  bf16* xb  = (bf16*)(ws);                 // 16.78 MB
  bf16* WaT = (bf16*)(ws + 16777216);      //  6.29 MB
  bf16* WpT = (bf16*)(ws + 23068672);      //  2.10 MB
  bf16* Qb  = (bf16*)(ws + 25165824);      // 16.78 MB (pre-scaled)
  bf16* Kb  = (bf16*)(ws + 41943040);      // 16.78 MB
  bf16* Vtb = (bf16*)(ws + 58720256);      // 16.78 MB (transposed [b,h,d,s])
  bf16* Yb  = (bf16*)(ws + 75497472);      // 16.78 MB

  cvt_f32_bf16<<<8192, 256, 0, stream>>>(x, xb, BATCH * SEQ * EMB);
  transpose_cvt2<<<dim3(128, 32), 256, 0, stream>>>(W_attn, W_proj, WaT, WpT);
  gemm_bt<128><<<dim3(24, 64), 256, 0, stream>>>(xb, WaT, b_attn, EMB, 3 * EMB, 0,
                                                 Qb, Kb, Vtb, nullptr);
  attn<<<dim3(16, BATCH * NH), 256, 0, stream>>>(Qb, Kb, Vtb, Yb);
  gemm_bt<64><<<dim3(16, 64), 256, 0, stream>>>(Yb, WpT, b_proj, EMB, EMB, 1,
                                                nullptr, nullptr, nullptr, out);
}

// Round 5
// 295.278 us; speedup vs baseline: 1.7286x; 1.7286x over previous
//
#include <hip/hip_runtime.h>

// CausalSelfAttention: x[4,2048,1024] fp32 -> out fp32
// Pipeline (all bf16 MFMA, fp32 accum):
//  1) cvt x -> bf16            2) transpose+cvt W_attn & W_proj -> bf16 [N][K]
//  3) gemm_bt + bias -> Q (pre-scaled by 0.125*log2e) [b,h,s,d], K [b,h,s,d],
//     V TRANSPOSED [b,h,d,s]  (all bf16)
//  4) flash attention: fixed-max softmax (P = 2^s), K/Vt staged direct-to-LDS
//     via global_load_lds w/ XOR source swizzle; P roundtrip through LDS.
//  5) gemm_bt(Y, W_projT) + bias -> out fp32
// MFMA 16x16x32 bf16 layouts (HW-verified per guide):
//   A: a[j] = A[m=lane&15][k=quad*8+j]  (quad=lane>>4)
//   B: b[j] = B[k=quad*8+j][n=lane&15]
//   C/D: c[i] = D[row=quad*4+i][col=lane&15]
//
// REGISTER BUDGET NOTE (R4 post-mortem): gemm needs ~120 unified regs/lane
// (64 AGPR acc + ~56 arch). min-waves=6 capped it at ~85 -> accumulator
// spill to scratch -> 923 MB WRITE_SIZE, 3x slower. min-waves=4 (128 regs)
// is the max occupancy that fits. DO NOT raise past 4 for the 128x128 tile.

#define BATCH 4
#define SEQ   2048
#define EMB   1024
#define NH    16
#define HD    64

typedef __bf16 bf16;
typedef __bf16 bf16x8 __attribute__((ext_vector_type(8)));
typedef float  f32x4  __attribute__((ext_vector_type(4)));
typedef unsigned int u32x4 __attribute__((ext_vector_type(4)));

// direct global->LDS 16B copy: LDS dest is wave-uniform base + lane*16
__device__ __forceinline__ void ld_lds16(const void* g, void* l) {
  __builtin_amdgcn_global_load_lds(
      (const __attribute__((address_space(1))) void*)g,
      (__attribute__((address_space(3))) void*)l, 16, 0, 0);
}

// ---------------- convert fp32 -> bf16 ----------------
__global__ void cvt_f32_bf16(const float* __restrict__ in, bf16* __restrict__ out, int n) {
  int i = (blockIdx.x * blockDim.x + threadIdx.x) * 4;
  if (i + 3 < n) {
    float4 v = *(const float4*)(in + i);
    bf16 o0 = (bf16)v.x, o1 = (bf16)v.y, o2 = (bf16)v.z, o3 = (bf16)v.w;
    out[i] = o0; out[i+1] = o1; out[i+2] = o2; out[i+3] = o3;
  }
}

// ---------------- transpose + convert both weights (one launch) ----------------
// W[K=1024][N] fp32 -> WT[N][K] bf16.  blockIdx.x<96 -> W_attn(N=3072), else W_proj.
__global__ void transpose_cvt2(const float* __restrict__ Wa, const float* __restrict__ Wp,
                               bf16* __restrict__ WaT, bf16* __restrict__ WpT) {
  __shared__ float tile[32][33];
  int bx = blockIdx.x;
  const float* W; bf16* WT; int N;
  if (bx < 96) { W = Wa; WT = WaT; N = 3072; }
  else         { W = Wp; WT = WpT; N = 1024; bx -= 96; }
  int n0 = bx * 32, k0 = blockIdx.y * 32;
  int tx = threadIdx.x & 31, ty = threadIdx.x >> 5; // ty: 0..7
#pragma unroll
  for (int r = 0; r < 4; r++) {
    int k = k0 + ty + r * 8;
    tile[ty + r * 8][tx] = W[(long)k * N + n0 + tx];
  }
  __syncthreads();
#pragma unroll
  for (int r = 0; r < 4; r++) {
    int n = n0 + ty + r * 8;
    WT[(long)n * EMB + k0 + tx] = (bf16)tile[tx][ty + r * 8];
  }
}

// ---------------- GEMM: A[M][K] bf16 x Bt[N][K] bf16 + bias ----------------
// 128 x BNT tile, BK=32, direct-to-LDS staging (lane-linear) with XOR source
// swizzle. min-waves=4: max occupancy without accumulator spill (see note).
#define QSCALE 0.18033688f   // (1/8) * log2(e): folds attn scale + exp2 conversion

template <int BNT>
__global__ __launch_bounds__(256, 4) void gemm_bt(
    const bf16* __restrict__ A, const bf16* __restrict__ Bt,
    const float* __restrict__ bias, int Kdim, int Ncols, int mode,
    bf16* __restrict__ q, bf16* __restrict__ k, bf16* __restrict__ v,
    float* __restrict__ out)
{
  constexpr int NF = BNT / 32;               // n-fragments per wave
  __shared__ __align__(16) bf16 Al[128 * 32];
  __shared__ __align__(16) bf16 Bl[BNT * 32];
  int m0 = blockIdx.y * 128;
  int n0 = blockIdx.x * BNT;
  int t = threadIdx.x;
  int wave = t >> 6, lane = t & 63;
  int l15 = lane & 15, quad = lane >> 4;
  int wm = (wave & 1) * 64, wn = (wave >> 1) * (BNT / 2);

  f32x4 acc[4][NF] = {};

  for (int kt = 0; kt < Kdim; kt += 32) {
    __syncthreads();
#pragma unroll
    for (int it = 0; it < 2; ++it) {
      int c = it * 256 + t;
      int row = c >> 2, u = c & 3;
      ld_lds16(&A[(long)(m0 + row) * Kdim + kt + ((u ^ (row & 3)) * 8)],
               &Al[(it * 256 + wave * 64) * 8]);
    }
#pragma unroll
    for (int it = 0; it < BNT / 64; ++it) {
      int c = it * 256 + t;
      int row = c >> 2, u = c & 3;
      ld_lds16(&Bt[(long)(n0 + row) * Kdim + kt + ((u ^ (row & 3)) * 8)],
               &Bl[(it * 256 + wave * 64) * 8]);
    }
    __syncthreads();
    bf16x8 af[4], bfr[NF];
#pragma unroll
    for (int i = 0; i < 4; ++i) {
      int r = wm + i * 16 + l15;
      af[i] = *(const bf16x8*)(&Al[r * 32 + ((quad ^ (r & 3)) * 8)]);
    }
#pragma unroll
    for (int i = 0; i < NF; ++i) {
      int r = wn + i * 16 + l15;
      bfr[i] = *(const bf16x8*)(&Bl[r * 32 + ((quad ^ (r & 3)) * 8)]);
    }
#pragma unroll
    for (int mi = 0; mi < 4; ++mi)
#pragma unroll
      for (int ni = 0; ni < NF; ++ni)
        acc[mi][ni] = __builtin_amdgcn_mfma_f32_16x16x32_bf16(af[mi], bfr[ni], acc[mi][ni], 0, 0, 0);
  }

  // epilogue
#pragma unroll
  for (int mi = 0; mi < 4; ++mi) {
#pragma unroll
    for (int ni = 0; ni < NF; ++ni) {
      int gcol = n0 + wn + ni * 16 + l15;
      float bv = bias[gcol];
#pragma unroll
      for (int i = 0; i < 4; ++i) {
        int grow = m0 + wm + mi * 16 + quad * 4 + i;
        float val = acc[mi][ni][i] + bv;
        if (mode == 0) {
          int which = gcol >> 10, e = gcol & 1023;
          int h = e >> 6, d = e & 63;
          int b = grow >> 11, s = grow & 2047;
          if (which == 0) {
            q[(((long)b * NH + h) * SEQ + s) * HD + d] = (bf16)(val * QSCALE);
          } else if (which == 1) {
            k[(((long)b * NH + h) * SEQ + s) * HD + d] = (bf16)val;
          } else {
            v[(((long)b * NH + h) * HD + d) * SEQ + s] = (bf16)val;  // V^T
          }
        } else {
          out[(long)grow * Ncols + gcol] = val;
        }
      }
    }
  }
}

// ---------------- flash attention ----------------
// grid (16, B*NH); block 256 = 4 waves; block runs strips i and 31-i (balanced).
// 64-key tiles; K and V^T staged direct-to-LDS with XOR source swizzle so the
// lane-linear layout reads conflict-free. Fixed-max softmax: P = 2^s
// (Q pre-scaled by 0.125*log2e), l deferred to epilogue.
__global__ __launch_bounds__(256, 4) void attn(
    const bf16* __restrict__ Q, const bf16* __restrict__ K,
    const bf16* __restrict__ Vt, bf16* __restrict__ Y)
{
  __shared__ __align__(16) bf16 Kl[64 * 64];       // [key][d], units swizzled by key&7
  __shared__ __align__(16) bf16 Vl[64 * 64];       // [d][key], units swizzled by d&7
  __shared__ __align__(16) bf16 Pl[4][16 * 64];    // per-wave [q][col^swz]
  int b = blockIdx.y >> 4, h = blockIdx.y & 15;
  const bf16* Qp  = Q  + (((long)b * NH + h) * SEQ) * HD;
  const bf16* Kp  = K  + (((long)b * NH + h) * SEQ) * HD;
  const bf16* Vtp = Vt + (((long)b * NH + h) * HD) * SEQ;
  int t = threadIdx.x, wave = t >> 6, lane = t & 63;
  int l15 = lane & 15, quad = lane >> 4;

#pragma unroll 1
  for (int pass = 0; pass < 2; ++pass) {
    int q0 = (pass == 0) ? blockIdx.x * 64 : (SEQ - 64) - blockIdx.x * 64;
    int wq0 = q0 + wave * 16;

    // Q fragments: A[m=l15][k=quad*8+j], k split 0/32 (Q pre-scaled)
    bf16x8 qf0, qf1;
    {
      const bf16* qrow = Qp + (long)(wq0 + l15) * HD + quad * 8;
      qf0 = *(const bf16x8*)(qrow);
      qf1 = *(const bf16x8*)(qrow + 32);
    }
    float lrow[4] = {0.f, 0.f, 0.f, 0.f};
    f32x4 oacc[4] = {};

    int ntiles = q0 / 64 + 1;
#pragma unroll 1
    for (int kt = 0; kt < ntiles; ++kt) {
      int k0 = kt * 64;
      __syncthreads();
      // stage K [key][d] and V^T [d][key]; source-swizzled: LDS unit
      // (row*8 + u) holds global chunk (u ^ (row&7)) of that row.
#pragma unroll
      for (int it = 0; it < 2; ++it) {
        int cu = it * 256 + t;
        int row = cu >> 3, u = cu & 7;
        ld_lds16(&Kp[(long)(k0 + row) * HD + ((u ^ (row & 7)) * 8)],
                 &Kl[(it * 256 + wave * 64) * 8]);
        ld_lds16(&Vtp[(long)row * SEQ + k0 + ((u ^ (row & 7)) * 8)],
                 &Vl[(it * 256 + wave * 64) * 8]);
      }
      __syncthreads();

      // scores: S[16q x 64k] = Q @ K^T  (4 n-frags x 2 k-steps)
      f32x4 s[4] = {};
#pragma unroll
      for (int kk = 0; kk < 2; ++kk) {
        bf16x8 qf = kk ? qf1 : qf0;
#pragma unroll
        for (int ni = 0; ni < 4; ++ni) {
          int r = ni * 16 + l15, u = kk * 4 + quad;
          bf16x8 kfr = *(const bf16x8*)(&Kl[r * 64 + ((u ^ (r & 7)) * 8)]);
          s[ni] = __builtin_amdgcn_mfma_f32_16x16x32_bf16(qf, kfr, s[ni], 0, 0, 0);
        }
      }

      bool full = (k0 + 63 <= wq0);   // wave-uniform
#pragma unroll
      for (int i = 0; i < 4; ++i) {
        int qr = wq0 + quad * 4 + i;
        float e[4];
#pragma unroll
        for (int ni = 0; ni < 4; ++ni) {
          float x = s[ni][i];
          if (!full) x = (k0 + ni * 16 + l15 <= qr) ? x : -1e30f;
          e[ni] = __builtin_amdgcn_exp2f(x);   // P = 2^(score*log2e/8)
        }
        lrow[i] += (e[0] + e[1]) + (e[2] + e[3]);
        int prow = (quad * 4 + i) * 64;   // store col' = col ^ (quad*16)
        Pl[wave][prow + ((0 ^ quad) * 16 + l15)] = (bf16)e[0];
        Pl[wave][prow + ((1 ^ quad) * 16 + l15)] = (bf16)e[1];
        Pl[wave][prow + ((2 ^ quad) * 16 + l15)] = (bf16)e[2];
        Pl[wave][prow + ((3 ^ quad) * 16 + l15)] = (bf16)e[3];
      }
      asm volatile("s_waitcnt lgkmcnt(0)" ::: "memory");
      // PV: P[16x64] @ V[64x64]
#pragma unroll
      for (int kk = 0; kk < 2; ++kk) {
        int kbase = kk * 32 + quad * 8;
        bf16x8 pf = *(const bf16x8*)(&Pl[wave][l15 * 64 + (kbase ^ ((l15 >> 2) * 16))]);
#pragma unroll
        for (int ni = 0; ni < 4; ++ni) {
          int dd = ni * 16 + l15, u = kk * 4 + quad;
          bf16x8 vf = *(const bf16x8*)(&Vl[dd * 64 + ((u ^ (dd & 7)) * 8)]);
          oacc[ni] = __builtin_amdgcn_mfma_f32_16x16x32_bf16(pf, vf, oacc[ni], 0, 0, 0);
        }
      }
    }
    // epilogue: reduce l across the 16 q-columns group, write Y bf16
#pragma unroll
    for (int i = 0; i < 4; ++i) {
      float rs = lrow[i];
#pragma unroll
      for (int off = 8; off; off >>= 1) rs += __shfl_xor(rs, off, 16);
      float inv = 1.0f / rs;
      int qr = wq0 + quad * 4 + i;
      bf16* dst = Y + ((long)(b * SEQ + qr)) * EMB + h * HD;
#pragma unroll
      for (int ni = 0; ni < 4; ++ni)
        dst[ni * 16 + l15] = (bf16)(oacc[ni][i] * inv);
    }
  }
}

extern "C" void kernel_launch(void* const* d_in, const int* in_sizes, int n_in,
                              void* d_out, int out_size, void* d_ws, size_t ws_size,
                              hipStream_t stream) {
  const float* x      = (const float*)d_in[0];
  const float* W_attn = (const float*)d_in[1];
  const float* b_attn = (const float*)d_in[2];
  const float* W_proj = (const float*)d_in[3];
  const float* b_proj = (const float*)d_in[4];
  float* out = (float*)d_out;
  char* ws = (char*)d_ws;
  bf16* xb  = (bf16*)(ws);                 // 16.78 MB
  bf16* WaT = (bf16*)(ws + 16777216);      //  6.29 MB
  bf16* WpT = (bf16*)(ws + 23068672);      //  2.10 MB
  bf16* Qb  = (bf16*)(ws + 25165824);      // 16.78 MB (pre-scaled)
  bf16* Kb  = (bf16*)(ws + 41943040);      // 16.78 MB
  bf16* Vtb = (bf16*)(ws + 58720256);      // 16.78 MB (transposed [b,h,d,s])
  bf16* Yb  = (bf16*)(ws + 75497472);      // 16.78 MB

  cvt_f32_bf16<<<8192, 256, 0, stream>>>(x, xb, BATCH * SEQ * EMB);
  transpose_cvt2<<<dim3(128, 32), 256, 0, stream>>>(W_attn, W_proj, WaT, WpT);
  gemm_bt<128><<<dim3(24, 64), 256, 0, stream>>>(xb, WaT, b_attn, EMB, 3 * EMB, 0,
                                                 Qb, Kb, Vtb, nullptr);
  attn<<<dim3(16, BATCH * NH), 256, 0, stream>>>(Qb, Kb, Vtb, Yb);
  gemm_bt<64><<<dim3(16, 64), 256, 0, stream>>>(Yb, WpT, b_proj, EMB, EMB, 1,
                                                nullptr, nullptr, nullptr, out);
}

// Round 6
// 271.730 us; speedup vs baseline: 1.8784x; 1.0867x over previous
//
#include <hip/hip_runtime.h>

// CausalSelfAttention: x[4,2048,1024] fp32 -> out fp32
// Pipeline (all bf16 MFMA, fp32 accum):
//  1) cvt x -> bf16            2) transpose+cvt W_attn & W_proj -> bf16 [N][K]
//  3) gemm_bt + bias -> Q (pre-scaled by 0.125*log2e) [b,h,s,d], K [b,h,s,d],
//     V TRANSPOSED [b,h,d,s]  (all bf16)
//  4) flash attention: fixed-max softmax (P = 2^s), 32 q-rows/wave,
//     K/Vt staged direct-to-LDS w/ XOR source swizzle.
//  5) gemm_bt(Y, W_projT) + bias -> out fp32
// MFMA 16x16x32 bf16 layouts (HW-verified per guide):
//   A: a[j] = A[m=lane&15][k=quad*8+j]  (quad=lane>>4)
//   B: b[j] = B[k=quad*8+j][n=lane&15]
//   C/D: c[i] = D[row=quad*4+i][col=lane&15]
//
// REGISTER BUDGET NOTE (R4/R5 post-mortem): gemm uses ~120 unified regs
// (64 AGPR acc + ~56 arch). launch_bounds min-waves only CAPS the allocator;
// it cannot raise occupancy. min-waves=6 forced a cap of ~85 -> acc spill ->
// 923 MB WRITE_SIZE, 3x slower. Use min-waves=3 (budget ~170): zero spill
// risk, actual occupancy follows actual reg use.
// R5 diagnosis: gemm1 is vmcnt(0)-before-barrier drain-bound (MfmaUtil 18.7%
// = one-wave-per-SIMD effective). This round: BK=64 (half the drains) +
// XCD-L2 swizzle (cheaper drains).

#define BATCH 4
#define SEQ   2048
#define EMB   1024
#define NH    16
#define HD    64

typedef __bf16 bf16;
typedef __bf16 bf16x8 __attribute__((ext_vector_type(8)));
typedef float  f32x4  __attribute__((ext_vector_type(4)));

// direct global->LDS 16B copy: LDS dest is wave-uniform base + lane*16
__device__ __forceinline__ void ld_lds16(const void* g, void* l) {
  __builtin_amdgcn_global_load_lds(
      (const __attribute__((address_space(1))) void*)g,
      (__attribute__((address_space(3))) void*)l, 16, 0, 0);
}

// ---------------- convert fp32 -> bf16 ----------------
__global__ void cvt_f32_bf16(const float* __restrict__ in, bf16* __restrict__ out, int n) {
  int i = (blockIdx.x * blockDim.x + threadIdx.x) * 4;
  if (i + 3 < n) {
    float4 v = *(const float4*)(in + i);
    bf16 o0 = (bf16)v.x, o1 = (bf16)v.y, o2 = (bf16)v.z, o3 = (bf16)v.w;
    out[i] = o0; out[i+1] = o1; out[i+2] = o2; out[i+3] = o3;
  }
}

// ---------------- transpose + convert both weights (one launch) ----------------
__global__ void transpose_cvt2(const float* __restrict__ Wa, const float* __restrict__ Wp,
                               bf16* __restrict__ WaT, bf16* __restrict__ WpT) {
  __shared__ float tile[32][33];
  int bx = blockIdx.x;
  const float* W; bf16* WT; int N;
  if (bx < 96) { W = Wa; WT = WaT; N = 3072; }
  else         { W = Wp; WT = WpT; N = 1024; bx -= 96; }
  int n0 = bx * 32, k0 = blockIdx.y * 32;
  int tx = threadIdx.x & 31, ty = threadIdx.x >> 5;
#pragma unroll
  for (int r = 0; r < 4; r++) {
    int k = k0 + ty + r * 8;
    tile[ty + r * 8][tx] = W[(long)k * N + n0 + tx];
  }
  __syncthreads();
#pragma unroll
  for (int r = 0; r < 4; r++) {
    int n = n0 + ty + r * 8;
    WT[(long)n * EMB + k0 + tx] = (bf16)tile[tx][ty + r * 8];
  }
}

// ---------------- GEMM: A[M][K] bf16 x Bt[N][K] bf16 + bias ----------------
// 128 x BNT tile, BK=64, direct-to-LDS staging, XOR source swizzle
// (physical 16B-unit row*8+u holds logical chunk u^(row&7); rows are 128 B so
// fragment reads spread all 32 banks). 1D grid with XCD-L2 swizzle.
#define QSCALE 0.18033688f   // (1/8) * log2(e)

template <int BNT>
__global__ __launch_bounds__(256, 3) void gemm_bt(
    const bf16* __restrict__ A, const bf16* __restrict__ Bt,
    const float* __restrict__ bias, int Kdim, int Ncols, int mode,
    bf16* __restrict__ q, bf16* __restrict__ k, bf16* __restrict__ v,
    float* __restrict__ out)
{
  constexpr int NF = BNT / 32;               // n-fragments per wave
  __shared__ __align__(16) bf16 Al[128 * 64];
  __shared__ __align__(16) bf16 Bl[BNT * 64];
  // XCD swizzle: consecutive blocks on one XCD share bx (B-tile hot in its L2)
  // and cover an 8-row by-band (A-rows hot). Bijective for grid = nbx*64.
  int lin = blockIdx.x;
  int xcd = lin & 7, s = lin >> 3;
  int bx = s >> 3, by = xcd * 8 + (s & 7);
  int m0 = by * 128;
  int n0 = bx * BNT;
  int t = threadIdx.x;
  int wave = t >> 6, lane = t & 63;
  int l15 = lane & 15, quad = lane >> 4;
  int wm = (wave & 1) * 64, wn = (wave >> 1) * (BNT / 2);

  f32x4 acc[4][NF] = {};

  for (int kt = 0; kt < Kdim; kt += 64) {
    __syncthreads();
#pragma unroll
    for (int it = 0; it < 4; ++it) {         // A: 128 rows x 8 units
      int c = it * 256 + t;
      int row = c >> 3, u = c & 7;
      ld_lds16(&A[(long)(m0 + row) * Kdim + kt + ((u ^ (row & 7)) * 8)],
               &Al[(it * 256 + wave * 64) * 8]);
    }
#pragma unroll
    for (int it = 0; it < BNT / 32; ++it) {  // B: BNT rows x 8 units
      int c = it * 256 + t;
      int row = c >> 3, u = c & 7;
      ld_lds16(&Bt[(long)(n0 + row) * Kdim + kt + ((u ^ (row & 7)) * 8)],
               &Bl[(it * 256 + wave * 64) * 8]);
    }
    __syncthreads();
#pragma unroll
    for (int ks = 0; ks < 2; ++ks) {
      bf16x8 af[4], bfr[NF];
#pragma unroll
      for (int i = 0; i < 4; ++i) {
        int r = wm + i * 16 + l15;
        af[i] = *(const bf16x8*)(&Al[r * 64 + (((ks * 4 + quad) ^ (r & 7)) * 8)]);
      }
#pragma unroll
      for (int i = 0; i < NF; ++i) {
        int r = wn + i * 16 + l15;
        bfr[i] = *(const bf16x8*)(&Bl[r * 64 + (((ks * 4 + quad) ^ (r & 7)) * 8)]);
      }
#pragma unroll
      for (int mi = 0; mi < 4; ++mi)
#pragma unroll
        for (int ni = 0; ni < NF; ++ni)
          acc[mi][ni] = __builtin_amdgcn_mfma_f32_16x16x32_bf16(af[mi], bfr[ni], acc[mi][ni], 0, 0, 0);
    }
  }

  // epilogue
#pragma unroll
  for (int mi = 0; mi < 4; ++mi) {
#pragma unroll
    for (int ni = 0; ni < NF; ++ni) {
      int gcol = n0 + wn + ni * 16 + l15;
      float bv = bias[gcol];
#pragma unroll
      for (int i = 0; i < 4; ++i) {
        int grow = m0 + wm + mi * 16 + quad * 4 + i;
        float val = acc[mi][ni][i] + bv;
        if (mode == 0) {
          int which = gcol >> 10, e = gcol & 1023;
          int h = e >> 6, d = e & 63;
          int b = grow >> 11, ss = grow & 2047;
          if (which == 0) {
            q[(((long)b * NH + h) * SEQ + ss) * HD + d] = (bf16)(val * QSCALE);
          } else if (which == 1) {
            k[(((long)b * NH + h) * SEQ + ss) * HD + d] = (bf16)val;
          } else {
            v[(((long)b * NH + h) * HD + d) * SEQ + ss] = (bf16)val;  // V^T
          }
        } else {
          out[(long)grow * Ncols + gcol] = val;
        }
      }
    }
  }
}

// ---------------- flash attention ----------------
// grid (16, B*NH); block 128 = 2 waves, 32 q-rows/wave (two 16-row m-frags).
// Block covers a 64-row strip; runs strips i and 31-i (uniform 33 tiles).
// 64-key tiles; K [key][d] and V^T [d][key] staged direct-to-LDS with XOR
// source swizzle (conflict-free b128 reads). Fixed-max softmax: P = 2^s.
#define LDP 72   // P row stride (elems), 144 B rows: conflict-free, 16B-aligned

__global__ __launch_bounds__(128, 3) void attn(
    const bf16* __restrict__ Q, const bf16* __restrict__ K,
    const bf16* __restrict__ Vt, bf16* __restrict__ Y)
{
  __shared__ __align__(16) bf16 Kl[64 * 64];        // 8 KB
  __shared__ __align__(16) bf16 Vl[64 * 64];        // 8 KB
  __shared__ __align__(16) bf16 Pl[2][32 * LDP];    // 9 KB, per-wave
  int b = blockIdx.y >> 4, h = blockIdx.y & 15;
  const bf16* Qp  = Q  + (((long)b * NH + h) * SEQ) * HD;
  const bf16* Kp  = K  + (((long)b * NH + h) * SEQ) * HD;
  const bf16* Vtp = Vt + (((long)b * NH + h) * HD) * SEQ;
  int t = threadIdx.x, wave = t >> 6, lane = t & 63;
  int l15 = lane & 15, quad = lane >> 4;

#pragma unroll 1
  for (int pass = 0; pass < 2; ++pass) {
    int q0 = (pass == 0) ? blockIdx.x * 64 : (SEQ - 64) - blockIdx.x * 64;
    int wq0 = q0 + wave * 32;

    // Q fragments: m-frag m covers rows wq0+m*16 .. +15; k split 0/32
    bf16x8 qf[2][2];
#pragma unroll
    for (int m = 0; m < 2; ++m) {
      const bf16* qrow = Qp + (long)(wq0 + m * 16 + l15) * HD + quad * 8;
      qf[m][0] = *(const bf16x8*)(qrow);
      qf[m][1] = *(const bf16x8*)(qrow + 32);
    }
    float lrow[2][4] = {};
    f32x4 oacc[2][4] = {};

    int ntiles = q0 / 64 + 1;
#pragma unroll 1
    for (int kt = 0; kt < ntiles; ++kt) {
      int k0 = kt * 64;
      __syncthreads();
      // stage K and V^T: physical unit row*8+u holds logical chunk u^(row&7)
#pragma unroll
      for (int it = 0; it < 4; ++it) {
        int cu = it * 128 + t;
        int row = cu >> 3, u = cu & 7;
        ld_lds16(&Kp[(long)(k0 + row) * HD + ((u ^ (row & 7)) * 8)],
                 &Kl[(it * 128 + wave * 64) * 8]);
        ld_lds16(&Vtp[(long)row * SEQ + k0 + ((u ^ (row & 7)) * 8)],
                 &Vl[(it * 128 + wave * 64) * 8]);
      }
      __syncthreads();

      // scores: S[32q x 64k]; kfr register-shared across both m-frags
      f32x4 sc[2][4] = {};
#pragma unroll
      for (int kk = 0; kk < 2; ++kk) {
#pragma unroll
        for (int ni = 0; ni < 4; ++ni) {
          int r = ni * 16 + l15, u = kk * 4 + quad;
          bf16x8 kfr = *(const bf16x8*)(&Kl[r * 64 + ((u ^ (r & 7)) * 8)]);
          sc[0][ni] = __builtin_amdgcn_mfma_f32_16x16x32_bf16(qf[0][kk], kfr, sc[0][ni], 0, 0, 0);
          sc[1][ni] = __builtin_amdgcn_mfma_f32_16x16x32_bf16(qf[1][kk], kfr, sc[1][ni], 0, 0, 0);
        }
      }

      bool full = (k0 + 63 <= wq0);   // wave-uniform (min row = wq0)
#pragma unroll
      for (int m = 0; m < 2; ++m) {
#pragma unroll
        for (int i = 0; i < 4; ++i) {
          int qr = wq0 + m * 16 + quad * 4 + i;
          float e[4];
#pragma unroll
          for (int ni = 0; ni < 4; ++ni) {
            float x = sc[m][ni][i];
            if (!full) x = (k0 + ni * 16 + l15 <= qr) ? x : -1e30f;
            e[ni] = __builtin_amdgcn_exp2f(x);
          }
          lrow[m][i] += (e[0] + e[1]) + (e[2] + e[3]);
          int prow = (m * 16 + quad * 4 + i) * LDP;
#pragma unroll
          for (int ni = 0; ni < 4; ++ni)
            Pl[wave][prow + ni * 16 + l15] = (bf16)e[ni];
        }
      }
      asm volatile("s_waitcnt lgkmcnt(0)" ::: "memory");
      // PV: P[32x64] @ V[64x64]; vf register-shared across both m-frags
#pragma unroll
      for (int kk = 0; kk < 2; ++kk) {
        int kbase = kk * 32 + quad * 8;
        bf16x8 pf0 = *(const bf16x8*)(&Pl[wave][(l15) * LDP + kbase]);
        bf16x8 pf1 = *(const bf16x8*)(&Pl[wave][(16 + l15) * LDP + kbase]);
#pragma unroll
        for (int ni = 0; ni < 4; ++ni) {
          int dd = ni * 16 + l15, u = kk * 4 + quad;
          bf16x8 vf = *(const bf16x8*)(&Vl[dd * 64 + ((u ^ (dd & 7)) * 8)]);
          oacc[0][ni] = __builtin_amdgcn_mfma_f32_16x16x32_bf16(pf0, vf, oacc[0][ni], 0, 0, 0);
          oacc[1][ni] = __builtin_amdgcn_mfma_f32_16x16x32_bf16(pf1, vf, oacc[1][ni], 0, 0, 0);
        }
      }
    }
    // epilogue: reduce l across the 16-lane column groups, write Y bf16
#pragma unroll
    for (int m = 0; m < 2; ++m) {
#pragma unroll
      for (int i = 0; i < 4; ++i) {
        float rs = lrow[m][i];
#pragma unroll
        for (int off = 8; off; off >>= 1) rs += __shfl_xor(rs, off, 16);
        float inv = 1.0f / rs;
        int qr = wq0 + m * 16 + quad * 4 + i;
        bf16* dst = Y + ((long)(b * SEQ + qr)) * EMB + h * HD;
#pragma unroll
        for (int ni = 0; ni < 4; ++ni)
          dst[ni * 16 + l15] = (bf16)(oacc[m][ni][i] * inv);
      }
    }
  }
}

extern "C" void kernel_launch(void* const* d_in, const int* in_sizes, int n_in,
                              void* d_out, int out_size, void* d_ws, size_t ws_size,
                              hipStream_t stream) {
  const float* x      = (const float*)d_in[0];
  const float* W_attn = (const float*)d_in[1];
  const float* b_attn = (const float*)d_in[2];
  const float* W_proj = (const float*)d_in[3];
  const float* b_proj = (const float*)d_in[4];
  float* out = (float*)d_out;
  char* ws = (char*)d_ws;
  bf16* xb  = (bf16*)(ws);                 // 16.78 MB
  bf16* WaT = (bf16*)(ws + 16777216);      //  6.29 MB
  bf16* WpT = (bf16*)(ws + 23068672);      //  2.10 MB
  bf16* Qb  = (bf16*)(ws + 25165824);      // 16.78 MB (pre-scaled)
  bf16* Kb  = (bf16*)(ws + 41943040);      // 16.78 MB
  bf16* Vtb = (bf16*)(ws + 58720256);      // 16.78 MB (transposed [b,h,d,s])
  bf16* Yb  = (bf16*)(ws + 75497472);      // 16.78 MB

  cvt_f32_bf16<<<8192, 256, 0, stream>>>(x, xb, BATCH * SEQ * EMB);
  transpose_cvt2<<<dim3(128, 32), 256, 0, stream>>>(W_attn, W_proj, WaT, WpT);
  gemm_bt<128><<<1536, 256, 0, stream>>>(xb, WaT, b_attn, EMB, 3 * EMB, 0,
                                         Qb, Kb, Vtb, nullptr);
  attn<<<dim3(16, BATCH * NH), 128, 0, stream>>>(Qb, Kb, Vtb, Yb);
  gemm_bt<64><<<1024, 256, 0, stream>>>(Yb, WpT, b_proj, EMB, EMB, 1,
                                        nullptr, nullptr, nullptr, out);
}

// Round 7
// 247.723 us; speedup vs baseline: 2.0604x; 1.0969x over previous
//
#include <hip/hip_runtime.h>

// CausalSelfAttention: x[4,2048,1024] fp32 -> out fp32
// Pipeline (all bf16 MFMA, fp32 accum):
//  1) cvt x -> bf16            2) transpose+cvt W_attn & W_proj -> bf16 [N][K]
//  3) gemm_bt + bias -> Q (pre-scaled by 0.125*log2e) [b,h,s,d], K [b,h,s,d],
//     V TRANSPOSED [b,h,d,s]  (all bf16)
//  4) flash attention: 128 q-rows/block (4 waves x 32), XCD head-affinity
//     swizzle, fixed-max softmax (P = 2^s), K/Vt direct-to-LDS w/ XOR swizzle.
//  5) gemm_bt(Y, W_projT) + bias -> out fp32
// MFMA 16x16x32 bf16 layouts (HW-verified per guide):
//   A: a[j] = A[m=lane&15][k=quad*8+j]  (quad=lane>>4)
//   B: b[j] = B[k=quad*8+j][n=lane&15]
//   C/D: c[i] = D[row=quad*4+i][col=lane&15]
//
// REGISTER BUDGET NOTE (R4/R5): gemm needs ~120 unified regs. min-waves=6
// forced a ~85-reg cap -> accumulator spill -> 923 MB WRITE_SIZE, 3x slower.
// Keep gemm at min-waves=3. launch_bounds cannot RAISE occupancy, only cap regs.
// R6 diagnosis: attn became K/V-refetch HBM-bound (257 MB FETCH, 92% of dur).
// This round: 128-row blocks (halve staging) + XCD head affinity (L2 reuse).

#define BATCH 4
#define SEQ   2048
#define EMB   1024
#define NH    16
#define HD    64

typedef __bf16 bf16;
typedef __bf16 bf16x8 __attribute__((ext_vector_type(8)));
typedef float  f32x4  __attribute__((ext_vector_type(4)));

// direct global->LDS 16B copy: LDS dest is wave-uniform base + lane*16
__device__ __forceinline__ void ld_lds16(const void* g, void* l) {
  __builtin_amdgcn_global_load_lds(
      (const __attribute__((address_space(1))) void*)g,
      (__attribute__((address_space(3))) void*)l, 16, 0, 0);
}

// ---------------- convert fp32 -> bf16 ----------------
__global__ void cvt_f32_bf16(const float* __restrict__ in, bf16* __restrict__ out, int n) {
  int i = (blockIdx.x * blockDim.x + threadIdx.x) * 4;
  if (i + 3 < n) {
    float4 v = *(const float4*)(in + i);
    bf16 o0 = (bf16)v.x, o1 = (bf16)v.y, o2 = (bf16)v.z, o3 = (bf16)v.w;
    out[i] = o0; out[i+1] = o1; out[i+2] = o2; out[i+3] = o3;
  }
}

// ---------------- transpose + convert both weights (one launch) ----------------
__global__ void transpose_cvt2(const float* __restrict__ Wa, const float* __restrict__ Wp,
                               bf16* __restrict__ WaT, bf16* __restrict__ WpT) {
  __shared__ float tile[32][33];
  int bx = blockIdx.x;
  const float* W; bf16* WT; int N;
  if (bx < 96) { W = Wa; WT = WaT; N = 3072; }
  else         { W = Wp; WT = WpT; N = 1024; bx -= 96; }
  int n0 = bx * 32, k0 = blockIdx.y * 32;
  int tx = threadIdx.x & 31, ty = threadIdx.x >> 5;
#pragma unroll
  for (int r = 0; r < 4; r++) {
    int k = k0 + ty + r * 8;
    tile[ty + r * 8][tx] = W[(long)k * N + n0 + tx];
  }
  __syncthreads();
#pragma unroll
  for (int r = 0; r < 4; r++) {
    int n = n0 + ty + r * 8;
    WT[(long)n * EMB + k0 + tx] = (bf16)tile[tx][ty + r * 8];
  }
}

// ---------------- GEMM: A[M][K] bf16 x Bt[N][K] bf16 + bias ----------------
// 128 x BNT tile, BK=64, direct-to-LDS staging, XOR source swizzle,
// XCD-L2 block swizzle.
#define QSCALE 0.18033688f   // (1/8) * log2(e)

template <int BNT>
__global__ __launch_bounds__(256, 3) void gemm_bt(
    const bf16* __restrict__ A, const bf16* __restrict__ Bt,
    const float* __restrict__ bias, int Kdim, int Ncols, int mode,
    bf16* __restrict__ q, bf16* __restrict__ k, bf16* __restrict__ v,
    float* __restrict__ out)
{
  constexpr int NF = BNT / 32;               // n-fragments per wave
  __shared__ __align__(16) bf16 Al[128 * 64];
  __shared__ __align__(16) bf16 Bl[BNT * 64];
  int lin = blockIdx.x;
  int xcd = lin & 7, s = lin >> 3;
  int bx = s >> 3, by = xcd * 8 + (s & 7);
  int m0 = by * 128;
  int n0 = bx * BNT;
  int t = threadIdx.x;
  int wave = t >> 6, lane = t & 63;
  int l15 = lane & 15, quad = lane >> 4;
  int wm = (wave & 1) * 64, wn = (wave >> 1) * (BNT / 2);

  f32x4 acc[4][NF] = {};

  for (int kt = 0; kt < Kdim; kt += 64) {
    __syncthreads();
#pragma unroll
    for (int it = 0; it < 4; ++it) {         // A: 128 rows x 8 units
      int c = it * 256 + t;
      int row = c >> 3, u = c & 7;
      ld_lds16(&A[(long)(m0 + row) * Kdim + kt + ((u ^ (row & 7)) * 8)],
               &Al[(it * 256 + wave * 64) * 8]);
    }
#pragma unroll
    for (int it = 0; it < BNT / 32; ++it) {  // B: BNT rows x 8 units
      int c = it * 256 + t;
      int row = c >> 3, u = c & 7;
      ld_lds16(&Bt[(long)(n0 + row) * Kdim + kt + ((u ^ (row & 7)) * 8)],
               &Bl[(it * 256 + wave * 64) * 8]);
    }
    __syncthreads();
#pragma unroll
    for (int ks = 0; ks < 2; ++ks) {
      bf16x8 af[4], bfr[NF];
#pragma unroll
      for (int i = 0; i < 4; ++i) {
        int r = wm + i * 16 + l15;
        af[i] = *(const bf16x8*)(&Al[r * 64 + (((ks * 4 + quad) ^ (r & 7)) * 8)]);
      }
#pragma unroll
      for (int i = 0; i < NF; ++i) {
        int r = wn + i * 16 + l15;
        bfr[i] = *(const bf16x8*)(&Bl[r * 64 + (((ks * 4 + quad) ^ (r & 7)) * 8)]);
      }
#pragma unroll
      for (int mi = 0; mi < 4; ++mi)
#pragma unroll
        for (int ni = 0; ni < NF; ++ni)
          acc[mi][ni] = __builtin_amdgcn_mfma_f32_16x16x32_bf16(af[mi], bfr[ni], acc[mi][ni], 0, 0, 0);
    }
  }

  // epilogue
#pragma unroll
  for (int mi = 0; mi < 4; ++mi) {
#pragma unroll
    for (int ni = 0; ni < NF; ++ni) {
      int gcol = n0 + wn + ni * 16 + l15;
      float bv = bias[gcol];
#pragma unroll
      for (int i = 0; i < 4; ++i) {
        int grow = m0 + wm + mi * 16 + quad * 4 + i;
        float val = acc[mi][ni][i] + bv;
        if (mode == 0) {
          int which = gcol >> 10, e = gcol & 1023;
          int h = e >> 6, d = e & 63;
          int b = grow >> 11, ss = grow & 2047;
          if (which == 0) {
            q[(((long)b * NH + h) * SEQ + ss) * HD + d] = (bf16)(val * QSCALE);
          } else if (which == 1) {
            k[(((long)b * NH + h) * SEQ + ss) * HD + d] = (bf16)val;
          } else {
            v[(((long)b * NH + h) * HD + d) * SEQ + ss] = (bf16)val;  // V^T
          }
        } else {
          out[(long)grow * Ncols + gcol] = val;
        }
      }
    }
  }
}

// ---------------- flash attention ----------------
// 1D grid 512 blocks; block 256 = 4 waves x 32 q-rows = 128-row strip.
// Decode: xcd=L&7, a=L>>3; head = xcd + 8*(a&7)  -> all 8 blocks of a head
// share L%8 (same XCD under round-robin dispatch; per-XCD L2 holds the head's
// 512 KB K/V). strip = a>>3; block runs strips st and 15-st (18 tiles each).
// 64-key tiles staged ONCE per block (shared by 4 waves) via global_load_lds.
#define LDP 72   // P row stride (elems): conflict-free, 16B-aligned

__global__ __launch_bounds__(256, 2) void attn(
    const bf16* __restrict__ Q, const bf16* __restrict__ K,
    const bf16* __restrict__ Vt, bf16* __restrict__ Y)
{
  __shared__ __align__(16) bf16 Kl[64 * 64];        // 8 KB
  __shared__ __align__(16) bf16 Vl[64 * 64];        // 8 KB
  __shared__ __align__(16) bf16 Pl[4][32 * LDP];    // 18 KB, per-wave
  int L = blockIdx.x;
  int a = L >> 3;
  int hd = (L & 7) + 8 * (a & 7);
  int st = a >> 3;
  int b = hd >> 4, h = hd & 15;
  const bf16* Qp  = Q  + (((long)b * NH + h) * SEQ) * HD;
  const bf16* Kp  = K  + (((long)b * NH + h) * SEQ) * HD;
  const bf16* Vtp = Vt + (((long)b * NH + h) * HD) * SEQ;
  int t = threadIdx.x, wave = t >> 6, lane = t & 63;
  int l15 = lane & 15, quad = lane >> 4;

#pragma unroll 1
  for (int pass = 0; pass < 2; ++pass) {
    int q0 = (pass == 0) ? st * 128 : (SEQ - 128) - st * 128;
    int wq0 = q0 + wave * 32;

    // Q fragments: m-frag m covers rows wq0+m*16 .. +15; k split 0/32
    bf16x8 qf[2][2];
#pragma unroll
    for (int m = 0; m < 2; ++m) {
      const bf16* qrow = Qp + (long)(wq0 + m * 16 + l15) * HD + quad * 8;
      qf[m][0] = *(const bf16x8*)(qrow);
      qf[m][1] = *(const bf16x8*)(qrow + 32);
    }
    float lrow[2][4] = {};
    f32x4 oacc[2][4] = {};

    int ntiles = q0 / 64 + 2;     // block's 128 rows need tiles through q0+127
#pragma unroll 1
    for (int kt = 0; kt < ntiles; ++kt) {
      int k0 = kt * 64;
      __syncthreads();
      // stage K [key][d], V^T [d][key]: unit row*8+u holds chunk u^(row&7)
#pragma unroll
      for (int it = 0; it < 2; ++it) {
        int cu = it * 256 + t;
        int row = cu >> 3, u = cu & 7;
        ld_lds16(&Kp[(long)(k0 + row) * HD + ((u ^ (row & 7)) * 8)],
                 &Kl[(it * 256 + wave * 64) * 8]);
        ld_lds16(&Vtp[(long)row * SEQ + k0 + ((u ^ (row & 7)) * 8)],
                 &Vl[(it * 256 + wave * 64) * 8]);
      }
      __syncthreads();
      if (k0 > wq0 + 31) continue;   // wave's rows all masked for this tile

      // scores: S[32q x 64k]; kfr register-shared across both m-frags
      f32x4 sc[2][4] = {};
#pragma unroll
      for (int kk = 0; kk < 2; ++kk) {
#pragma unroll
        for (int ni = 0; ni < 4; ++ni) {
          int r = ni * 16 + l15, u = kk * 4 + quad;
          bf16x8 kfr = *(const bf16x8*)(&Kl[r * 64 + ((u ^ (r & 7)) * 8)]);
          sc[0][ni] = __builtin_amdgcn_mfma_f32_16x16x32_bf16(qf[0][kk], kfr, sc[0][ni], 0, 0, 0);
          sc[1][ni] = __builtin_amdgcn_mfma_f32_16x16x32_bf16(qf[1][kk], kfr, sc[1][ni], 0, 0, 0);
        }
      }

      bool full = (k0 + 63 <= wq0);   // wave-uniform (min row = wq0)
#pragma unroll
      for (int m = 0; m < 2; ++m) {
#pragma unroll
        for (int i = 0; i < 4; ++i) {
          int qr = wq0 + m * 16 + quad * 4 + i;
          float e[4];
#pragma unroll
          for (int ni = 0; ni < 4; ++ni) {
            float x = sc[m][ni][i];
            if (!full) x = (k0 + ni * 16 + l15 <= qr) ? x : -1e30f;
            e[ni] = __builtin_amdgcn_exp2f(x);
          }
          lrow[m][i] += (e[0] + e[1]) + (e[2] + e[3]);
          int prow = (m * 16 + quad * 4 + i) * LDP;
#pragma unroll
          for (int ni = 0; ni < 4; ++ni)
            Pl[wave][prow + ni * 16 + l15] = (bf16)e[ni];
        }
      }
      asm volatile("s_waitcnt lgkmcnt(0)" ::: "memory");
      // PV: P[32x64] @ V[64x64]; vf register-shared across both m-frags
#pragma unroll
      for (int kk = 0; kk < 2; ++kk) {
        int kbase = kk * 32 + quad * 8;
        bf16x8 pf0 = *(const bf16x8*)(&Pl[wave][(l15) * LDP + kbase]);
        bf16x8 pf1 = *(const bf16x8*)(&Pl[wave][(16 + l15) * LDP + kbase]);
#pragma unroll
        for (int ni = 0; ni < 4; ++ni) {
          int dd = ni * 16 + l15, u = kk * 4 + quad;
          bf16x8 vf = *(const bf16x8*)(&Vl[dd * 64 + ((u ^ (dd & 7)) * 8)]);
          oacc[0][ni] = __builtin_amdgcn_mfma_f32_16x16x32_bf16(pf0, vf, oacc[0][ni], 0, 0, 0);
          oacc[1][ni] = __builtin_amdgcn_mfma_f32_16x16x32_bf16(pf1, vf, oacc[1][ni], 0, 0, 0);
        }
      }
    }
    // epilogue: reduce l across the 16-lane column groups, write Y bf16
#pragma unroll
    for (int m = 0; m < 2; ++m) {
#pragma unroll
      for (int i = 0; i < 4; ++i) {
        float rs = lrow[m][i];
#pragma unroll
        for (int off = 8; off; off >>= 1) rs += __shfl_xor(rs, off, 16);
        float inv = 1.0f / rs;
        int qr = wq0 + m * 16 + quad * 4 + i;
        bf16* dst = Y + ((long)(b * SEQ + qr)) * EMB + h * HD;
#pragma unroll
        for (int ni = 0; ni < 4; ++ni)
          dst[ni * 16 + l15] = (bf16)(oacc[m][ni][i] * inv);
      }
    }
  }
}

extern "C" void kernel_launch(void* const* d_in, const int* in_sizes, int n_in,
                              void* d_out, int out_size, void* d_ws, size_t ws_size,
                              hipStream_t stream) {
  const float* x      = (const float*)d_in[0];
  const float* W_attn = (const float*)d_in[1];
  const float* b_attn = (const float*)d_in[2];
  const float* W_proj = (const float*)d_in[3];
  const float* b_proj = (const float*)d_in[4];
  float* out = (float*)d_out;
  char* ws = (char*)d_ws;
  bf16* xb  = (bf16*)(ws);                 // 16.78 MB
  bf16* WaT = (bf16*)(ws + 16777216);      //  6.29 MB
  bf16* WpT = (bf16*)(ws + 23068672);      //  2.10 MB
  bf16* Qb  = (bf16*)(ws + 25165824);      // 16.78 MB (pre-scaled)
  bf16* Kb  = (bf16*)(ws + 41943040);      // 16.78 MB
  bf16* Vtb = (bf16*)(ws + 58720256);      // 16.78 MB (transposed [b,h,d,s])
  bf16* Yb  = (bf16*)(ws + 75497472);      // 16.78 MB

  cvt_f32_bf16<<<8192, 256, 0, stream>>>(x, xb, BATCH * SEQ * EMB);
  transpose_cvt2<<<dim3(128, 32), 256, 0, stream>>>(W_attn, W_proj, WaT, WpT);
  gemm_bt<128><<<1536, 256, 0, stream>>>(xb, WaT, b_attn, EMB, 3 * EMB, 0,
                                         Qb, Kb, Vtb, nullptr);
  attn<<<512, 256, 0, stream>>>(Qb, Kb, Vtb, Yb);
  gemm_bt<64><<<1024, 256, 0, stream>>>(Yb, WpT, b_proj, EMB, EMB, 1,
                                        nullptr, nullptr, nullptr, out);
}